// Round 2
// baseline (238.064 us; speedup 1.0000x reference)
//
#include <hip/hip_runtime.h>
#include <stdint.h>

typedef unsigned short u16;
typedef __attribute__((ext_vector_type(8))) short bfrag8;       // 8 x bf16 (MFMA operand)
typedef __attribute__((ext_vector_type(4))) float f32x4;        // MFMA accumulator
typedef __attribute__((ext_vector_type(8))) unsigned short u16x8;
typedef __attribute__((ext_vector_type(4))) unsigned short u16x4;

__device__ __forceinline__ u16 f2bf(float f) {
  union { float f; uint32_t u; } v; v.f = f;
  return (u16)((v.u + 0x7FFFu + ((v.u >> 16) & 1u)) >> 16);   // RNE
}

// ---------------- fp32 -> bf16 convert, batched (7 tensors, 1 launch) ----------------
struct CvtJob { const float* src; u16* dst; int n4; };
struct CvtBatch { CvtJob j[7]; };

__global__ void cvt_batch(CvtBatch b) {
  CvtJob jb = b.j[blockIdx.y];
  int i = blockIdx.x * blockDim.x + threadIdx.x;
  if (i >= jb.n4) return;
  float4 v = reinterpret_cast<const float4*>(jb.src)[i];
  u16x4 o;
  o[0] = f2bf(v.x); o[1] = f2bf(v.y); o[2] = f2bf(v.z); o[3] = f2bf(v.w);
  reinterpret_cast<u16x4*>(jb.dst)[i] = o;
}

// ---------------- NT GEMM: C = A(M,K) @ W(N,K)^T + bias, M=4096,N=1024,K=1024 ----------------
struct Gemm3 {
  const u16* A[3];
  const u16* W[3];
  const float* bias[3];
  void* C[3];
};

template<int OUT_F32>
__global__ __launch_bounds__(256, 2) void gemm_nt_bias(Gemm3 g) {
  constexpr int K = 1024, N = 1024;
  constexpr int BK = 32, LDT = BK + 8;   // +8 bf16 pad -> 80B row stride, conflict-free b128 reads
  __shared__ u16 As[128 * LDT];
  __shared__ u16 Bs[128 * LDT];
  const int z = blockIdx.z;
  const u16* __restrict__ A = g.A[z];
  const u16* __restrict__ W = g.W[z];
  const float* __restrict__ bias = g.bias[z];
  const int tid = threadIdx.x;
  const int lane = tid & 63;
  const int lr = lane & 15, lg = lane >> 4;
  const int wave = tid >> 6;
  const int wr = (wave >> 1) * 64, wc = (wave & 1) * 64;  // 2x2 wave grid, 64x64 each
  const int bm = blockIdx.x * 128, bn = blockIdx.y * 128;

  f32x4 acc[4][4] = {};

  for (int k0 = 0; k0 < K; k0 += BK) {
    // stage 128x32 A-tile and B-tile: 512 units of 16B, 2 per thread
#pragma unroll
    for (int i = 0; i < 2; i++) {
      int u = tid + 256 * i;
      int row = u >> 2, kg = (u & 3) * 8;
      *(u16x8*)&As[row * LDT + kg] = *(const u16x8*)(A + (size_t)(bm + row) * K + k0 + kg);
      *(u16x8*)&Bs[row * LDT + kg] = *(const u16x8*)(W + (size_t)(bn + row) * K + k0 + kg);
    }
    __syncthreads();
    bfrag8 af[4], bf[4];
#pragma unroll
    for (int mi = 0; mi < 4; mi++)
      af[mi] = *(const bfrag8*)&As[(wr + mi * 16 + lr) * LDT + lg * 8];
#pragma unroll
    for (int ni = 0; ni < 4; ni++)
      bf[ni] = *(const bfrag8*)&Bs[(wc + ni * 16 + lr) * LDT + lg * 8];
#pragma unroll
    for (int mi = 0; mi < 4; mi++)
#pragma unroll
      for (int ni = 0; ni < 4; ni++)
        acc[mi][ni] = __builtin_amdgcn_mfma_f32_16x16x32_bf16(af[mi], bf[ni], acc[mi][ni], 0, 0, 0);
    __syncthreads();
  }

  // epilogue: C/D layout col=lane&15, row=(lane>>4)*4+r
  const int col0 = bn + wc + lr;
#pragma unroll
  for (int ni = 0; ni < 4; ni++) {
    int col = col0 + ni * 16;
    float bv = bias[col];
#pragma unroll
    for (int mi = 0; mi < 4; mi++) {
      int row = bm + wr + mi * 16 + lg * 4;
#pragma unroll
      for (int r = 0; r < 4; r++) {
        float v = acc[mi][ni][r] + bv;
        if (OUT_F32)
          ((float*)g.C[z])[(size_t)(row + r) * N + col] = v;
        else
          ((u16*)g.C[z])[(size_t)(row + r) * N + col] = f2bf(v);
      }
    }
  }
}

// ---------------- V transpose: per bh, (2048,64) -> VT[64][2048] ----------------
// grid (32 k-tiles, 32 bh), 256 threads; 64x64 LDS tile.
__global__ void vtrans_kernel(const u16* __restrict__ Vp, u16* __restrict__ VT) {
  __shared__ u16 T[64][66];   // stride 132B: scalar transpose writes ~4-way max
  const int kt = blockIdx.x, bh = blockIdx.y;
  const int tid = threadIdx.x;
  const u16* src = Vp + (size_t)bh * 131072 + (size_t)kt * 64 * 64;
#pragma unroll
  for (int i = 0; i < 2; i++) {
    int u = tid + 256 * i;
    int row = u >> 3, c = (u & 7) * 8;
    u16x8 v = *(const u16x8*)(src + row * 64 + c);
#pragma unroll
    for (int j = 0; j < 8; j++) T[c + j][row] = v[j];
  }
  __syncthreads();
  u16* dst = VT + (size_t)bh * 131072 + (size_t)kt * 64;
#pragma unroll
  for (int i = 0; i < 2; i++) {
    int u = tid + 256 * i;
    int d = u >> 3, c = (u & 7) * 8;
    u16x8 o = *(const u16x8*)&T[d][c];
    *(u16x8*)(dst + (size_t)d * 2048 + c) = o;
  }
}

// ---------------- causal flash attention per (b,h): Q,K contiguous (2048,64), VT (64,2048) ------
// 1-D grid of 512; 4 independent waves per block (no barriers); wave w owns q rows
// [qt*128 + w*32, +32). K/V read directly from global (L2-resident per head).
__global__ __launch_bounds__(256, 3) void attn_kernel(
    const u16* __restrict__ Qp, const u16* __restrict__ Kp,
    const u16* __restrict__ VT, u16* __restrict__ X)
{
  constexpr int LDP = 132;           // bank-conflict-free for both P writes and b128 reads
  __shared__ u16 Ps[4][32][LDP];     // per-wave P tile (32 q-rows x 128 kpos)

  // balanced schedule: co-resident pair (id, id+256) gets qt and 15-qt (17 units per CU);
  // each XCD sees only 4 bh values (2MB K/V -> L2-fit).
  const int id = blockIdx.x;
  const int xcd = id & 7, rr = id >> 3;
  const int bh = xcd * 4 + (rr & 3);
  const int qidx = rr >> 2;                       // 0..15
  const int qt = qidx < 8 ? qidx : 23 - qidx;     // pairs (j, 15-j) across halves

  const size_t base = (size_t)bh * 131072;
  const u16* __restrict__ Qb = Qp + base;
  const u16* __restrict__ Kb = Kp + base;
  const u16* __restrict__ Vtb = VT + base;
  const int tid = threadIdx.x, lane = tid & 63, w = tid >> 6;
  const int lr = lane & 15, lg = lane >> 4;

  // Q fragments in registers
  bfrag8 qf[2][2];
#pragma unroll
  for (int mi = 0; mi < 2; mi++)
#pragma unroll
    for (int ds = 0; ds < 2; ds++)
      qf[mi][ds] = *(const bfrag8*)(Qb + (size_t)(qt * 128 + w * 32 + mi * 16 + lr) * 64 + ds * 32 + lg * 8);

  f32x4 oacc[2][4] = {};
  float m_run[2][4], l_run[2][4];
#pragma unroll
  for (int mi = 0; mi < 2; mi++)
#pragma unroll
    for (int r = 0; r < 4; r++) { m_run[mi][r] = -INFINITY; l_run[mi][r] = 0.f; }

  const float SCALE = 0.03125f;  // 1/sqrt(1024)

  for (int kt = 0; kt <= qt; kt++) {
    // ---- S = Q K^T (K frags straight from global/L2) ----
    f32x4 sacc[2][8];
#pragma unroll
    for (int mi = 0; mi < 2; mi++)
#pragma unroll
      for (int kf = 0; kf < 8; kf++) sacc[mi][kf] = (f32x4){0.f, 0.f, 0.f, 0.f};
#pragma unroll
    for (int kf = 0; kf < 8; kf++) {
      const u16* kr = Kb + (size_t)(kt * 128 + kf * 16 + lr) * 64 + lg * 8;
      bfrag8 kb0 = *(const bfrag8*)kr;
      bfrag8 kb1 = *(const bfrag8*)(kr + 32);
#pragma unroll
      for (int mi = 0; mi < 2; mi++) {
        sacc[mi][kf] = __builtin_amdgcn_mfma_f32_16x16x32_bf16(qf[mi][0], kb0, sacc[mi][kf], 0, 0, 0);
        sacc[mi][kf] = __builtin_amdgcn_mfma_f32_16x16x32_bf16(qf[mi][1], kb1, sacc[mi][kf], 0, 0, 0);
      }
    }

    // ---- scale + causal mask (diagonal tile only) ----
    const bool diag = (kt == qt);
#pragma unroll
    for (int mi = 0; mi < 2; mi++)
#pragma unroll
      for (int kf = 0; kf < 8; kf++)
#pragma unroll
        for (int r = 0; r < 4; r++) {
          float x = sacc[mi][kf][r] * SCALE;
          if (diag) {
            int qg = w * 32 + mi * 16 + lg * 4 + r;
            int kg = kf * 16 + lr;
            if (kg > qg) x = -INFINITY;
          }
          sacc[mi][kf][r] = x;
        }

    // ---- online softmax; P -> per-wave LDS (no barrier: wave-internal only) ----
#pragma unroll
    for (int mi = 0; mi < 2; mi++) {
#pragma unroll
      for (int r = 0; r < 4; r++) {
        float mt = sacc[mi][0][r];
#pragma unroll
        for (int kf = 1; kf < 8; kf++) mt = fmaxf(mt, sacc[mi][kf][r]);
        mt = fmaxf(mt, __shfl_xor(mt, 1));
        mt = fmaxf(mt, __shfl_xor(mt, 2));
        mt = fmaxf(mt, __shfl_xor(mt, 4));
        mt = fmaxf(mt, __shfl_xor(mt, 8));
        float mnew = fmaxf(m_run[mi][r], mt);
        float corr = __expf(m_run[mi][r] - mnew);   // first tile: exp(-inf)=0
        m_run[mi][r] = mnew;
        l_run[mi][r] *= corr;
#pragma unroll
        for (int df = 0; df < 4; df++) oacc[mi][df][r] *= corr;
        float rs = 0.f;
#pragma unroll
        for (int kf = 0; kf < 8; kf++) {
          float p = __expf(sacc[mi][kf][r] - mnew);  // masked: exp(-inf)=0
          rs += p;
          Ps[w][mi * 16 + lg * 4 + r][kf * 16 + lr] = f2bf(p);
        }
        rs += __shfl_xor(rs, 1);
        rs += __shfl_xor(rs, 2);
        rs += __shfl_xor(rs, 4);
        rs += __shfl_xor(rs, 8);
        l_run[mi][r] += rs;
      }
    }

    // ---- O += P V (A from Ps, B = VT rows straight from global/L2) ----
#pragma unroll
    for (int ks = 0; ks < 4; ks++) {
      bfrag8 pa0 = *(const bfrag8*)&Ps[w][lr][ks * 32 + lg * 8];
      bfrag8 pa1 = *(const bfrag8*)&Ps[w][16 + lr][ks * 32 + lg * 8];
#pragma unroll
      for (int df = 0; df < 4; df++) {
        bfrag8 vf = *(const bfrag8*)(Vtb + (size_t)(df * 16 + lr) * 2048 + kt * 128 + ks * 32 + lg * 8);
        oacc[0][df] = __builtin_amdgcn_mfma_f32_16x16x32_bf16(pa0, vf, oacc[0][df], 0, 0, 0);
        oacc[1][df] = __builtin_amdgcn_mfma_f32_16x16x32_bf16(pa1, vf, oacc[1][df], 0, 0, 0);
      }
    }
  }

  // ---- normalize and write X (head-contiguous layout == raw-view merge) ----
#pragma unroll
  for (int mi = 0; mi < 2; mi++) {
#pragma unroll
    for (int r = 0; r < 4; r++) {
      float inv = 1.0f / l_run[mi][r];
      int row = qt * 128 + w * 32 + mi * 16 + lg * 4 + r;
#pragma unroll
      for (int df = 0; df < 4; df++)
        X[base + (size_t)row * 64 + df * 16 + lr] = f2bf(oacc[mi][df][r] * inv);
    }
  }
}

extern "C" void kernel_launch(void* const* d_in, const int* in_sizes, int n_in,
                              void* d_out, int out_size, void* d_ws, size_t ws_size,
                              hipStream_t stream) {
  const float* key   = (const float*)d_in[0];
  const float* query = (const float*)d_in[1];
  const float* value = (const float*)d_in[2];
  const float* Wq = (const float*)d_in[4];
  const float* bq = (const float*)d_in[5];
  const float* Wk = (const float*)d_in[6];
  const float* bk = (const float*)d_in[7];
  const float* Wv = (const float*)d_in[8];
  const float* bv = (const float*)d_in[9];
  const float* Wo = (const float*)d_in[10];
  const float* bo = (const float*)d_in[11];

  u16* ws = (u16*)d_ws;
  const size_t MD = 4096ull * 1024ull;          // 4M elems
  u16* qb  = ws;                                 // query bf16
  u16* kb  = ws + MD;                            // key bf16
  u16* vbf = ws + 2 * MD;                        // value bf16 (reused as VT after g1)
  u16* Qp  = ws + 3 * MD;                        // projected Q
  u16* Kp  = ws + 4 * MD;
  u16* Vp  = ws + 5 * MD;
  u16* Xb  = ws + 6 * MD;                        // attention output
  u16* wqb = ws + 7 * MD;                        // weights bf16 (1M each)
  u16* wkb = wqb + 1024 * 1024;
  u16* wvb = wkb + 1024 * 1024;
  u16* wob = wvb + 1024 * 1024;

  CvtBatch cb;
  cb.j[0] = { query, qb, 1048576 };
  cb.j[1] = { key,   kb, 1048576 };
  cb.j[2] = { value, vbf, 1048576 };
  cb.j[3] = { Wq, wqb, 262144 };
  cb.j[4] = { Wk, wkb, 262144 };
  cb.j[5] = { Wv, wvb, 262144 };
  cb.j[6] = { Wo, wob, 262144 };
  cvt_batch<<<dim3(4096, 7), 256, 0, stream>>>(cb);

  Gemm3 g1;
  g1.A[0] = qb;  g1.A[1] = kb;  g1.A[2] = vbf;
  g1.W[0] = wqb; g1.W[1] = wkb; g1.W[2] = wvb;
  g1.bias[0] = bq; g1.bias[1] = bk; g1.bias[2] = bv;
  g1.C[0] = Qp; g1.C[1] = Kp; g1.C[2] = Vp;
  gemm_nt_bias<0><<<dim3(32, 8, 3), 256, 0, stream>>>(g1);

  // V -> per-head transpose (vbf slot is dead after g1)
  u16* VT = vbf;
  vtrans_kernel<<<dim3(32, 32), 256, 0, stream>>>(Vp, VT);

  attn_kernel<<<512, 256, 0, stream>>>(Qp, Kp, VT, Xb);

  Gemm3 g2;
  g2.A[0] = Xb; g2.W[0] = wob; g2.bias[0] = bo; g2.C[0] = d_out;
  g2.A[1] = g2.A[2] = nullptr; g2.W[1] = g2.W[2] = nullptr;
  g2.bias[1] = g2.bias[2] = nullptr; g2.C[1] = g2.C[2] = nullptr;
  gemm_nt_bias<1><<<dim3(32, 8, 1), 256, 0, stream>>>(g2);
}

// Round 3
// 173.286 us; speedup vs baseline: 1.3738x; 1.3738x over previous
//
#include <hip/hip_runtime.h>
#include <stdint.h>

typedef unsigned short u16;
typedef __attribute__((ext_vector_type(8))) short bfrag8;       // 8 x bf16 (MFMA operand)
typedef __attribute__((ext_vector_type(4))) float f32x4;        // MFMA accumulator
typedef __attribute__((ext_vector_type(8))) unsigned short u16x8;
typedef __attribute__((ext_vector_type(4))) unsigned short u16x4;

__device__ __forceinline__ u16 f2bf(float f) {
  union { float f; uint32_t u; } v; v.f = f;
  return (u16)((v.u + 0x7FFFu + ((v.u >> 16) & 1u)) >> 16);   // RNE
}

// async global->LDS, 16B per lane; LDS dest is wave-uniform base + lane*16
__device__ __forceinline__ void gload16(const void* g, void* l) {
  __builtin_amdgcn_global_load_lds(
      (const __attribute__((address_space(1))) void*)g,
      (__attribute__((address_space(3))) void*)l, 16, 0, 0);
}

// ---------------- fp32 -> bf16 convert, batched (7 tensors, 1 launch) ----------------
struct CvtJob { const float* src; u16* dst; int n4; };
struct CvtBatch { CvtJob j[7]; };

__global__ void cvt_batch(CvtBatch b) {
  CvtJob jb = b.j[blockIdx.y];
  int i = blockIdx.x * blockDim.x + threadIdx.x;
  if (i >= jb.n4) return;
  float4 v = reinterpret_cast<const float4*>(jb.src)[i];
  u16x4 o;
  o[0] = f2bf(v.x); o[1] = f2bf(v.y); o[2] = f2bf(v.z); o[3] = f2bf(v.w);
  reinterpret_cast<u16x4*>(jb.dst)[i] = o;
}

// ---------------- NT GEMM: C = A(M,K) @ W(N,K)^T + bias, M=4096,N=1024,K=1024 ----------------
struct Gemm3 {
  const u16* A[3];
  const u16* W[3];
  const float* bias[3];
  void* C[3];
};

template<int OUT_F32>
__global__ __launch_bounds__(256, 2) void gemm_nt_bias(Gemm3 g) {
  constexpr int K = 1024, N = 1024;
  constexpr int BK = 32, LDT = BK + 8;   // +8 bf16 pad -> 80B row stride, conflict-free b128 reads
  __shared__ u16 As[128 * LDT];
  __shared__ u16 Bs[128 * LDT];
  const int z = blockIdx.z;
  const u16* __restrict__ A = g.A[z];
  const u16* __restrict__ W = g.W[z];
  const float* __restrict__ bias = g.bias[z];
  const int tid = threadIdx.x;
  const int lane = tid & 63;
  const int lr = lane & 15, lg = lane >> 4;
  const int wave = tid >> 6;
  const int wr = (wave >> 1) * 64, wc = (wave & 1) * 64;  // 2x2 wave grid, 64x64 each
  const int bm = blockIdx.x * 128, bn = blockIdx.y * 128;

  f32x4 acc[4][4] = {};

  for (int k0 = 0; k0 < K; k0 += BK) {
#pragma unroll
    for (int i = 0; i < 2; i++) {
      int u = tid + 256 * i;
      int row = u >> 2, kg = (u & 3) * 8;
      *(u16x8*)&As[row * LDT + kg] = *(const u16x8*)(A + (size_t)(bm + row) * K + k0 + kg);
      *(u16x8*)&Bs[row * LDT + kg] = *(const u16x8*)(W + (size_t)(bn + row) * K + k0 + kg);
    }
    __syncthreads();
    bfrag8 af[4], bf[4];
#pragma unroll
    for (int mi = 0; mi < 4; mi++)
      af[mi] = *(const bfrag8*)&As[(wr + mi * 16 + lr) * LDT + lg * 8];
#pragma unroll
    for (int ni = 0; ni < 4; ni++)
      bf[ni] = *(const bfrag8*)&Bs[(wc + ni * 16 + lr) * LDT + lg * 8];
#pragma unroll
    for (int mi = 0; mi < 4; mi++)
#pragma unroll
      for (int ni = 0; ni < 4; ni++)
        acc[mi][ni] = __builtin_amdgcn_mfma_f32_16x16x32_bf16(af[mi], bf[ni], acc[mi][ni], 0, 0, 0);
    __syncthreads();
  }

  const int col0 = bn + wc + lr;
#pragma unroll
  for (int ni = 0; ni < 4; ni++) {
    int col = col0 + ni * 16;
    float bv = bias[col];
#pragma unroll
    for (int mi = 0; mi < 4; mi++) {
      int row = bm + wr + mi * 16 + lg * 4;
#pragma unroll
      for (int r = 0; r < 4; r++) {
        float v = acc[mi][ni][r] + bv;
        if (OUT_F32)
          ((float*)g.C[z])[(size_t)(row + r) * N + col] = v;
        else
          ((u16*)g.C[z])[(size_t)(row + r) * N + col] = f2bf(v);
      }
    }
  }
}

// ---------------- V transpose: per bh, (2048,64) -> VT[64][2048] ----------------
__global__ void vtrans_kernel(const u16* __restrict__ Vp, u16* __restrict__ VT) {
  __shared__ u16 T[64][66];
  const int kt = blockIdx.x, bh = blockIdx.y;
  const int tid = threadIdx.x;
  const u16* src = Vp + (size_t)bh * 131072 + (size_t)kt * 64 * 64;
#pragma unroll
  for (int i = 0; i < 2; i++) {
    int u = tid + 256 * i;
    int row = u >> 3, c = (u & 7) * 8;
    u16x8 v = *(const u16x8*)(src + row * 64 + c);
#pragma unroll
    for (int j = 0; j < 8; j++) T[c + j][row] = v[j];
  }
  __syncthreads();
  u16* dst = VT + (size_t)bh * 131072 + (size_t)kt * 64;
#pragma unroll
  for (int i = 0; i < 2; i++) {
    int u = tid + 256 * i;
    int d = u >> 3, c = (u & 7) * 8;
    u16x8 o = *(const u16x8*)&T[d][c];
    *(u16x8*)(dst + (size_t)d * 2048 + c) = o;
  }
}

// ---------------- causal flash attention per (b,h) ----------------
// Q,K contiguous (2048,64); VT (64,2048). Block: 4 waves, q-tile 128 (wave w: rows w*32..+32).
// KVBLK=64, double-buffered K/VT staged via global_load_lds with XOR-swizzled source chunks
// (linear LDS dest + same XOR on ds_read = rule "both-sides-or-neither").
__global__ __launch_bounds__(256, 2) void attn_kernel(
    const u16* __restrict__ Qp, const u16* __restrict__ Kp,
    const u16* __restrict__ VT, u16* __restrict__ X)
{
  __shared__ __align__(16) u16 Ks[2][64][64];   // 16 KB
  __shared__ __align__(16) u16 Vs[2][64][64];   // 16 KB  (rows = d, cols = kpos slice)
  constexpr int LDP = 72;                        // 144B stride: 16B-aligned, ~2-way banks
  __shared__ __align__(16) u16 Ps[4][32][LDP];   // 18 KB, per-wave P tile

  // balanced schedule: co-resident pair (id, id+256) -> qt and 15-qt (36 tile-units/CU);
  // each XCD sees 4 bh values (K+VT = 2MB -> L2-fit).
  const int id = blockIdx.x;
  const int xcd = id & 7, rr = id >> 3;
  const int bh = xcd * 4 + (rr & 3);
  const int qidx = rr >> 2;
  const int qt = qidx < 8 ? qidx : 23 - qidx;

  const size_t base = (size_t)bh * 131072;
  const u16* __restrict__ Qb = Qp + base;
  const u16* __restrict__ Kb = Kp + base;
  const u16* __restrict__ Vtb = VT + base;
  const int tid = threadIdx.x, lane = tid & 63, w = tid >> 6;
  const int lr = lane & 15, lg = lane >> 4;

  // staging geometry: per issue a wave fills 8 LDS rows (8x128B); lane -> (row=lane>>3,
  // slot=lane&7); source chunk pre-swizzled so LDS slot s of row r holds global chunk s^(r&7)
  const int srow = lane >> 3;                 // 0..7
  const int schunk = (lane & 7) ^ srow;       // inverse-swizzled source chunk

  // Q fragments in registers
  bfrag8 qf[2][2];
#pragma unroll
  for (int mi = 0; mi < 2; mi++)
#pragma unroll
    for (int ds = 0; ds < 2; ds++)
      qf[mi][ds] = *(const bfrag8*)(Qb + (size_t)(qt * 128 + w * 32 + mi * 16 + lr) * 64 + ds * 32 + lg * 8);

  f32x4 oacc[2][4] = {};
  float m_run[2][4], l_run[2][4];
#pragma unroll
  for (int mi = 0; mi < 2; mi++)
#pragma unroll
    for (int r = 0; r < 4; r++) { m_run[mi][r] = -INFINITY; l_run[mi][r] = 0.f; }

  const float SCALE = 0.03125f;  // 1/sqrt(1024)

  const int ktmax = 2 * qt + 1;                            // last kv-tile for the block
  const int w_ktmax = (qt * 128 + w * 32 + 31) >> 6;       // last kv-tile this wave needs

  auto STAGE = [&](int kt, int bufi) {
    // wave w stages rows w*16 .. w*16+15 of both tiles (2 issues each)
    const u16* gk = Kb + (size_t)(kt * 64 + w * 16 + srow) * 64 + schunk * 8;
    gload16(gk,       &Ks[bufi][w * 16][0]);
    gload16(gk + 512, &Ks[bufi][w * 16 + 8][0]);
    const u16* gv = Vtb + (size_t)(w * 16 + srow) * 2048 + kt * 64 + schunk * 8;
    gload16(gv,            &Vs[bufi][w * 16][0]);
    gload16(gv + 8 * 2048, &Vs[bufi][w * 16 + 8][0]);
  };

  STAGE(0, 0);
  __syncthreads();   // drains vmcnt -> tile 0 ready
  int buf = 0;

  for (int kt = 0; kt <= ktmax; kt++) {
    if (kt < ktmax) STAGE(kt + 1, buf ^ 1);   // prefetch next tile (completes under compute)

    if (kt <= w_ktmax) {
      // ---- S = Q K^T ----
      f32x4 sacc[2][4];
#pragma unroll
      for (int mi = 0; mi < 2; mi++)
#pragma unroll
        for (int kf = 0; kf < 4; kf++) sacc[mi][kf] = (f32x4){0.f, 0.f, 0.f, 0.f};
#pragma unroll
      for (int kf = 0; kf < 4; kf++) {
        const int krow = kf * 16 + lr;
        bfrag8 kb0 = *(const bfrag8*)&Ks[buf][krow][((lg) ^ (krow & 7)) * 8];
        bfrag8 kb1 = *(const bfrag8*)&Ks[buf][krow][((lg + 4) ^ (krow & 7)) * 8];
#pragma unroll
        for (int mi = 0; mi < 2; mi++) {
          sacc[mi][kf] = __builtin_amdgcn_mfma_f32_16x16x32_bf16(qf[mi][0], kb0, sacc[mi][kf], 0, 0, 0);
          sacc[mi][kf] = __builtin_amdgcn_mfma_f32_16x16x32_bf16(qf[mi][1], kb1, sacc[mi][kf], 0, 0, 0);
        }
      }

      // ---- causal mask (raw -inf; only tiles that touch the diagonal) ----
      if (kt * 64 + 63 > qt * 128 + w * 32) {
#pragma unroll
        for (int mi = 0; mi < 2; mi++)
#pragma unroll
          for (int kf = 0; kf < 4; kf++)
#pragma unroll
            for (int r = 0; r < 4; r++) {
              int qg = qt * 128 + w * 32 + mi * 16 + lg * 4 + r;
              int kg = kt * 64 + kf * 16 + lr;
              if (kg > qg) sacc[mi][kf][r] = -INFINITY;
            }
      }

      // ---- online softmax (scale folded into exp via fma); P -> per-wave LDS ----
#pragma unroll
      for (int mi = 0; mi < 2; mi++) {
#pragma unroll
        for (int r = 0; r < 4; r++) {
          float mt = fmaxf(fmaxf(sacc[mi][0][r], sacc[mi][1][r]),
                           fmaxf(sacc[mi][2][r], sacc[mi][3][r]));
          mt = fmaxf(mt, __shfl_xor(mt, 1));
          mt = fmaxf(mt, __shfl_xor(mt, 2));
          mt = fmaxf(mt, __shfl_xor(mt, 4));
          mt = fmaxf(mt, __shfl_xor(mt, 8));
          float mnew = fmaxf(m_run[mi][r], mt * SCALE);
          float corr = __expf(m_run[mi][r] - mnew);   // first tile: exp(-inf)=0
          m_run[mi][r] = mnew;
          l_run[mi][r] *= corr;
#pragma unroll
          for (int df = 0; df < 4; df++) oacc[mi][df][r] *= corr;
          float rs = 0.f;
#pragma unroll
          for (int kf = 0; kf < 4; kf++) {
            float p = __expf(__builtin_fmaf(sacc[mi][kf][r], SCALE, -mnew));
            rs += p;
            Ps[w][mi * 16 + lg * 4 + r][kf * 16 + lr] = f2bf(p);
          }
          rs += __shfl_xor(rs, 1);
          rs += __shfl_xor(rs, 2);
          rs += __shfl_xor(rs, 4);
          rs += __shfl_xor(rs, 8);
          l_run[mi][r] += rs;
        }
      }

      // ---- O += P V ----
#pragma unroll
      for (int ks = 0; ks < 2; ks++) {
        bfrag8 pa0 = *(const bfrag8*)&Ps[w][lr][ks * 32 + lg * 8];
        bfrag8 pa1 = *(const bfrag8*)&Ps[w][16 + lr][ks * 32 + lg * 8];
#pragma unroll
        for (int df = 0; df < 4; df++) {
          const int vrow = df * 16 + lr;
          bfrag8 vf = *(const bfrag8*)&Vs[buf][vrow][((ks * 4 + lg) ^ (vrow & 7)) * 8];
          oacc[0][df] = __builtin_amdgcn_mfma_f32_16x16x32_bf16(pa0, vf, oacc[0][df], 0, 0, 0);
          oacc[1][df] = __builtin_amdgcn_mfma_f32_16x16x32_bf16(pa1, vf, oacc[1][df], 0, 0, 0);
        }
      }
    }

    __syncthreads();   // drains prefetch vmcnt + syncs buffers
    buf ^= 1;
  }

  // ---- normalize and write X ----
#pragma unroll
  for (int mi = 0; mi < 2; mi++) {
#pragma unroll
    for (int r = 0; r < 4; r++) {
      float inv = 1.0f / l_run[mi][r];
      int row = qt * 128 + w * 32 + mi * 16 + lg * 4 + r;
#pragma unroll
      for (int df = 0; df < 4; df++)
        X[base + (size_t)row * 64 + df * 16 + lr] = f2bf(oacc[mi][df][r] * inv);
    }
  }
}

extern "C" void kernel_launch(void* const* d_in, const int* in_sizes, int n_in,
                              void* d_out, int out_size, void* d_ws, size_t ws_size,
                              hipStream_t stream) {
  const float* key   = (const float*)d_in[0];
  const float* query = (const float*)d_in[1];
  const float* value = (const float*)d_in[2];
  const float* Wq = (const float*)d_in[4];
  const float* bq = (const float*)d_in[5];
  const float* Wk = (const float*)d_in[6];
  const float* bk = (const float*)d_in[7];
  const float* Wv = (const float*)d_in[8];
  const float* bv = (const float*)d_in[9];
  const float* Wo = (const float*)d_in[10];
  const float* bo = (const float*)d_in[11];

  u16* ws = (u16*)d_ws;
  const size_t MD = 4096ull * 1024ull;
  u16* qb  = ws;
  u16* kb  = ws + MD;
  u16* vbf = ws + 2 * MD;   // value bf16 (reused as VT after g1)
  u16* Qp  = ws + 3 * MD;
  u16* Kp  = ws + 4 * MD;
  u16* Vp  = ws + 5 * MD;
  u16* Xb  = ws + 6 * MD;
  u16* wqb = ws + 7 * MD;
  u16* wkb = wqb + 1024 * 1024;
  u16* wvb = wkb + 1024 * 1024;
  u16* wob = wvb + 1024 * 1024;

  CvtBatch cb;
  cb.j[0] = { query, qb, 1048576 };
  cb.j[1] = { key,   kb, 1048576 };
  cb.j[2] = { value, vbf, 1048576 };
  cb.j[3] = { Wq, wqb, 262144 };
  cb.j[4] = { Wk, wkb, 262144 };
  cb.j[5] = { Wv, wvb, 262144 };
  cb.j[6] = { Wo, wob, 262144 };
  cvt_batch<<<dim3(4096, 7), 256, 0, stream>>>(cb);

  Gemm3 g1;
  g1.A[0] = qb;  g1.A[1] = kb;  g1.A[2] = vbf;
  g1.W[0] = wqb; g1.W[1] = wkb; g1.W[2] = wvb;
  g1.bias[0] = bq; g1.bias[1] = bk; g1.bias[2] = bv;
  g1.C[0] = Qp; g1.C[1] = Kp; g1.C[2] = Vp;
  gemm_nt_bias<0><<<dim3(32, 8, 3), 256, 0, stream>>>(g1);

  u16* VT = vbf;
  vtrans_kernel<<<dim3(32, 32), 256, 0, stream>>>(Vp, VT);

  attn_kernel<<<512, 256, 0, stream>>>(Qp, Kp, VT, Xb);

  Gemm3 g2;
  g2.A[0] = Xb; g2.W[0] = wob; g2.bias[0] = bo; g2.C[0] = d_out;
  g2.A[1] = g2.A[2] = nullptr; g2.W[1] = g2.W[2] = nullptr;
  g2.bias[1] = g2.bias[2] = nullptr; g2.C[1] = g2.C[2] = nullptr;
  gemm_nt_bias<1><<<dim3(32, 8, 1), 256, 0, stream>>>(g2);
}

// Round 4
// 159.178 us; speedup vs baseline: 1.4956x; 1.0886x over previous
//
#include <hip/hip_runtime.h>
#include <stdint.h>

typedef unsigned short u16;
typedef __attribute__((ext_vector_type(8))) short bfrag8;       // 8 x bf16 (MFMA operand)
typedef __attribute__((ext_vector_type(4))) float f32x4;        // MFMA accumulator
typedef __attribute__((ext_vector_type(8))) unsigned short u16x8;
typedef __attribute__((ext_vector_type(4))) unsigned short u16x4;

__device__ __forceinline__ u16 f2bf(float f) {
  union { float f; uint32_t u; } v; v.f = f;
  return (u16)((v.u + 0x7FFFu + ((v.u >> 16) & 1u)) >> 16);   // RNE
}

// async global->LDS, 16B per lane; LDS dest is wave-uniform base + lane*16
__device__ __forceinline__ void gload16(const void* g, void* l) {
  __builtin_amdgcn_global_load_lds(
      (const __attribute__((address_space(1))) void*)g,
      (__attribute__((address_space(3))) void*)l, 16, 0, 0);
}

// ---------------- fp32 -> bf16 convert, batched (7 tensors, 1 launch) ----------------
struct CvtJob { const float* src; u16* dst; int n4; };
struct CvtBatch { CvtJob j[7]; };

__global__ void cvt_batch(CvtBatch b) {
  CvtJob jb = b.j[blockIdx.y];
  int i = blockIdx.x * blockDim.x + threadIdx.x;
  if (i >= jb.n4) return;
  float4 v = reinterpret_cast<const float4*>(jb.src)[i];
  u16x4 o;
  o[0] = f2bf(v.x); o[1] = f2bf(v.y); o[2] = f2bf(v.z); o[3] = f2bf(v.w);
  reinterpret_cast<u16x4*>(jb.dst)[i] = o;
}

// ---------------- NT GEMM: C = A(M,K) @ W(N,K)^T + bias, M=4096,N=1024,K=1024 ----------------
struct Gemm3 {
  const u16* A[3];
  const u16* W[3];
  const float* bias[3];
  void* C[3];
};

template<int OUT_F32>
__global__ __launch_bounds__(256, 2) void gemm_nt_bias(Gemm3 g) {
  constexpr int K = 1024, N = 1024;
  constexpr int BK = 32, LDT = BK + 8;   // +8 bf16 pad -> 80B row stride, conflict-free b128 reads
  __shared__ u16 As[128 * LDT];
  __shared__ u16 Bs[128 * LDT];
  const int z = blockIdx.z;
  const u16* __restrict__ A = g.A[z];
  const u16* __restrict__ W = g.W[z];
  const float* __restrict__ bias = g.bias[z];
  const int tid = threadIdx.x;
  const int lane = tid & 63;
  const int lr = lane & 15, lg = lane >> 4;
  const int wave = tid >> 6;
  const int wr = (wave >> 1) * 64, wc = (wave & 1) * 64;  // 2x2 wave grid, 64x64 each
  const int bm = blockIdx.x * 128, bn = blockIdx.y * 128;

  f32x4 acc[4][4] = {};

  for (int k0 = 0; k0 < K; k0 += BK) {
#pragma unroll
    for (int i = 0; i < 2; i++) {
      int u = tid + 256 * i;
      int row = u >> 2, kg = (u & 3) * 8;
      *(u16x8*)&As[row * LDT + kg] = *(const u16x8*)(A + (size_t)(bm + row) * K + k0 + kg);
      *(u16x8*)&Bs[row * LDT + kg] = *(const u16x8*)(W + (size_t)(bn + row) * K + k0 + kg);
    }
    __syncthreads();
    bfrag8 af[4], bf[4];
#pragma unroll
    for (int mi = 0; mi < 4; mi++)
      af[mi] = *(const bfrag8*)&As[(wr + mi * 16 + lr) * LDT + lg * 8];
#pragma unroll
    for (int ni = 0; ni < 4; ni++)
      bf[ni] = *(const bfrag8*)&Bs[(wc + ni * 16 + lr) * LDT + lg * 8];
#pragma unroll
    for (int mi = 0; mi < 4; mi++)
#pragma unroll
      for (int ni = 0; ni < 4; ni++)
        acc[mi][ni] = __builtin_amdgcn_mfma_f32_16x16x32_bf16(af[mi], bf[ni], acc[mi][ni], 0, 0, 0);
    __syncthreads();
  }

  const int col0 = bn + wc + lr;
#pragma unroll
  for (int ni = 0; ni < 4; ni++) {
    int col = col0 + ni * 16;
    float bv = bias[col];
#pragma unroll
    for (int mi = 0; mi < 4; mi++) {
      int row = bm + wr + mi * 16 + lg * 4;
#pragma unroll
      for (int r = 0; r < 4; r++) {
        float v = acc[mi][ni][r] + bv;
        if (OUT_F32)
          ((float*)g.C[z])[(size_t)(row + r) * N + col] = v;
        else
          ((u16*)g.C[z])[(size_t)(row + r) * N + col] = f2bf(v);
      }
    }
  }
}

// ---------------- V transpose: per bh, (2048,64) -> VT[64][2048]; also zeroes work-queue ctr ----
__global__ void vtrans_kernel(const u16* __restrict__ Vp, u16* __restrict__ VT,
                              unsigned* __restrict__ ctr) {
  if (blockIdx.x == 0 && blockIdx.y == 0 && threadIdx.x == 0) *ctr = 0u;
  __shared__ u16 T[64][66];
  const int kt = blockIdx.x, bh = blockIdx.y;
  const int tid = threadIdx.x;
  const u16* src = Vp + (size_t)bh * 131072 + (size_t)kt * 64 * 64;
#pragma unroll
  for (int i = 0; i < 2; i++) {
    int u = tid + 256 * i;
    int row = u >> 3, c = (u & 7) * 8;
    u16x8 v = *(const u16x8*)(src + row * 64 + c);
#pragma unroll
    for (int j = 0; j < 8; j++) T[c + j][row] = v[j];
  }
  __syncthreads();
  u16* dst = VT + (size_t)bh * 131072 + (size_t)kt * 64;
#pragma unroll
  for (int i = 0; i < 2; i++) {
    int u = tid + 256 * i;
    int d = u >> 3, c = (u & 7) * 8;
    u16x8 o = *(const u16x8*)&T[d][c];
    *(u16x8*)(dst + (size_t)d * 2048 + c) = o;
  }
}

// ---------------- causal flash attention, persistent blocks + LPT work queue ----------------
// Unit = (bh, j): 64 q-rows [j*64, j*64+64) of head bh; KV range = tiles 0..j (KVBLK=64).
// 1024 units, heavy-first (j=31 first). 768 persistent blocks (3/CU), 4 waves each;
// wave w owns q rows [j*64 + w*16, +16). K/VT staged via swizzled global_load_lds (round-3).
__global__ __launch_bounds__(256, 3) void attn_kernel(
    const u16* __restrict__ Qp, const u16* __restrict__ Kp,
    const u16* __restrict__ VT, u16* __restrict__ X,
    unsigned* __restrict__ ctr)
{
  __shared__ __align__(16) u16 Ks[2][64][64];   // 16 KB
  __shared__ __align__(16) u16 Vs[2][64][64];   // 16 KB  (rows = d, cols = kpos slice)
  constexpr int LDP = 72;                        // 144B stride (9x16B): aligned b128, ~2-way banks
  __shared__ __align__(16) u16 Ps[4][16][LDP];   // 9 KB, per-wave P tile (16 q-rows x 64 kpos)
  __shared__ unsigned s_unit;

  const int tid = threadIdx.x, lane = tid & 63, w = tid >> 6;
  const int lr = lane & 15, lg = lane >> 4;
  // staging geometry: lane -> (row=lane>>3, slot=lane&7); source chunk pre-swizzled so
  // LDS slot s of row r holds global chunk s^(r&7) (linear LDS dest, same XOR on reads)
  const int srow = lane >> 3;
  const int schunk = (lane & 7) ^ srow;
  const float SCALE = 0.03125f;  // 1/sqrt(1024)

  for (;;) {
    __syncthreads();                 // previous unit's LDS reads + s_unit use complete
    if (tid == 0) s_unit = atomicAdd(ctr, 1u);
    __syncthreads();
    const unsigned u = s_unit;
    if (u >= 1024u) return;
    const int j = 31 - (int)(u >> 5);           // heavy-first: j=31 grabbed first
    const int bh = (int)(u & 31u);
    const size_t base = (size_t)bh * 131072;
    const u16* __restrict__ Qb = Qp + base;
    const u16* __restrict__ Kb = Kp + base;
    const u16* __restrict__ Vtb = VT + base;
    const int qrow0 = j * 64 + w * 16;          // wave's first q row

    // Q fragments
    bfrag8 qf[2];
#pragma unroll
    for (int ds = 0; ds < 2; ds++)
      qf[ds] = *(const bfrag8*)(Qb + (size_t)(qrow0 + lr) * 64 + ds * 32 + lg * 8);

    f32x4 oacc[4] = {};
    float m_run[4], l_run[4];
#pragma unroll
    for (int r = 0; r < 4; r++) { m_run[r] = -INFINITY; l_run[r] = 0.f; }

    auto STAGE = [&](int kt, int bufi) {
      const u16* gk = Kb + (size_t)(kt * 64 + w * 16 + srow) * 64 + schunk * 8;
      gload16(gk,       &Ks[bufi][w * 16][0]);
      gload16(gk + 512, &Ks[bufi][w * 16 + 8][0]);
      const u16* gv = Vtb + (size_t)(w * 16 + srow) * 2048 + kt * 64 + schunk * 8;
      gload16(gv,            &Vs[bufi][w * 16][0]);
      gload16(gv + 8 * 2048, &Vs[bufi][w * 16 + 8][0]);
    };

    STAGE(0, 0);
    __syncthreads();   // tile 0 ready
    int buf = 0;

    for (int kt = 0; kt <= j; kt++) {
      if (kt < j) STAGE(kt + 1, buf ^ 1);   // prefetch completes under compute

      // ---- S = Q K^T ----
      f32x4 sacc[4];
#pragma unroll
      for (int kf = 0; kf < 4; kf++) sacc[kf] = (f32x4){0.f, 0.f, 0.f, 0.f};
#pragma unroll
      for (int kf = 0; kf < 4; kf++) {
        const int krow = kf * 16 + lr;
        bfrag8 kb0 = *(const bfrag8*)&Ks[buf][krow][((lg) ^ (krow & 7)) * 8];
        bfrag8 kb1 = *(const bfrag8*)&Ks[buf][krow][((lg + 4) ^ (krow & 7)) * 8];
        sacc[kf] = __builtin_amdgcn_mfma_f32_16x16x32_bf16(qf[0], kb0, sacc[kf], 0, 0, 0);
        sacc[kf] = __builtin_amdgcn_mfma_f32_16x16x32_bf16(qf[1], kb1, sacc[kf], 0, 0, 0);
      }

      // ---- causal mask (only the diagonal tile kt==j can mask) ----
      if (kt == j) {
#pragma unroll
        for (int kf = 0; kf < 4; kf++)
#pragma unroll
          for (int r = 0; r < 4; r++) {
            int qg = qrow0 + lg * 4 + r;
            int kg = kt * 64 + kf * 16 + lr;
            if (kg > qg) sacc[kf][r] = -INFINITY;
          }
      }

      // ---- online softmax (scale folded into exp); P -> per-wave LDS ----
#pragma unroll
      for (int r = 0; r < 4; r++) {
        float mt = fmaxf(fmaxf(sacc[0][r], sacc[1][r]), fmaxf(sacc[2][r], sacc[3][r]));
        mt = fmaxf(mt, __shfl_xor(mt, 1));
        mt = fmaxf(mt, __shfl_xor(mt, 2));
        mt = fmaxf(mt, __shfl_xor(mt, 4));
        mt = fmaxf(mt, __shfl_xor(mt, 8));
        float mnew = fmaxf(m_run[r], mt * SCALE);
        float corr = __expf(m_run[r] - mnew);   // first tile: exp(-inf)=0
        m_run[r] = mnew;
        l_run[r] *= corr;
#pragma unroll
        for (int df = 0; df < 4; df++) oacc[df][r] *= corr;
        float rs = 0.f;
#pragma unroll
        for (int kf = 0; kf < 4; kf++) {
          float p = __expf(__builtin_fmaf(sacc[kf][r], SCALE, -mnew));
          rs += p;
          Ps[w][lg * 4 + r][kf * 16 + lr] = f2bf(p);
        }
        rs += __shfl_xor(rs, 1);
        rs += __shfl_xor(rs, 2);
        rs += __shfl_xor(rs, 4);
        rs += __shfl_xor(rs, 8);
        l_run[r] += rs;
      }

      // ---- O += P V ----
#pragma unroll
      for (int ks = 0; ks < 2; ks++) {
        bfrag8 pa = *(const bfrag8*)&Ps[w][lr][ks * 32 + lg * 8];
#pragma unroll
        for (int df = 0; df < 4; df++) {
          const int vrow = df * 16 + lr;
          bfrag8 vf = *(const bfrag8*)&Vs[buf][vrow][((ks * 4 + lg) ^ (vrow & 7)) * 8];
          oacc[df] = __builtin_amdgcn_mfma_f32_16x16x32_bf16(pa, vf, oacc[df], 0, 0, 0);
        }
      }

      __syncthreads();   // drains prefetch vmcnt + buffer handoff
      buf ^= 1;
    }

    // ---- normalize and write X ----
#pragma unroll
    for (int r = 0; r < 4; r++) {
      float inv = 1.0f / l_run[r];
      int row = qrow0 + lg * 4 + r;
#pragma unroll
      for (int df = 0; df < 4; df++)
        X[base + (size_t)row * 64 + df * 16 + lr] = f2bf(oacc[df][r] * inv);
    }
  }
}

extern "C" void kernel_launch(void* const* d_in, const int* in_sizes, int n_in,
                              void* d_out, int out_size, void* d_ws, size_t ws_size,
                              hipStream_t stream) {
  const float* key   = (const float*)d_in[0];
  const float* query = (const float*)d_in[1];
  const float* value = (const float*)d_in[2];
  const float* Wq = (const float*)d_in[4];
  const float* bq = (const float*)d_in[5];
  const float* Wk = (const float*)d_in[6];
  const float* bk = (const float*)d_in[7];
  const float* Wv = (const float*)d_in[8];
  const float* bv = (const float*)d_in[9];
  const float* Wo = (const float*)d_in[10];
  const float* bo = (const float*)d_in[11];

  u16* ws = (u16*)d_ws;
  const size_t MD = 4096ull * 1024ull;
  u16* qb  = ws;                   // query bf16 (dead after g1; first 4B reused as queue ctr)
  u16* kb  = ws + MD;
  u16* vbf = ws + 2 * MD;          // value bf16 (reused as VT after g1)
  u16* Qp  = ws + 3 * MD;
  u16* Kp  = ws + 4 * MD;
  u16* Vp  = ws + 5 * MD;
  u16* Xb  = ws + 6 * MD;
  u16* wqb = ws + 7 * MD;
  u16* wkb = wqb + 1024 * 1024;
  u16* wvb = wkb + 1024 * 1024;
  u16* wob = wvb + 1024 * 1024;

  CvtBatch cb;
  cb.j[0] = { query, qb, 1048576 };
  cb.j[1] = { key,   kb, 1048576 };
  cb.j[2] = { value, vbf, 1048576 };
  cb.j[3] = { Wq, wqb, 262144 };
  cb.j[4] = { Wk, wkb, 262144 };
  cb.j[5] = { Wv, wvb, 262144 };
  cb.j[6] = { Wo, wob, 262144 };
  cvt_batch<<<dim3(4096, 7), 256, 0, stream>>>(cb);

  Gemm3 g1;
  g1.A[0] = qb;  g1.A[1] = kb;  g1.A[2] = vbf;
  g1.W[0] = wqb; g1.W[1] = wkb; g1.W[2] = wvb;
  g1.bias[0] = bq; g1.bias[1] = bk; g1.bias[2] = bv;
  g1.C[0] = Qp; g1.C[1] = Kp; g1.C[2] = Vp;
  gemm_nt_bias<0><<<dim3(32, 8, 3), 256, 0, stream>>>(g1);

  u16* VT = vbf;
  unsigned* ctr = (unsigned*)qb;   // qb dead after g1
  vtrans_kernel<<<dim3(32, 32), 256, 0, stream>>>(Vp, VT, ctr);

  attn_kernel<<<768, 256, 0, stream>>>(Qp, Kp, VT, Xb, ctr);

  Gemm3 g2;
  g2.A[0] = Xb; g2.W[0] = wob; g2.bias[0] = bo; g2.C[0] = d_out;
  g2.A[1] = g2.A[2] = nullptr; g2.W[1] = g2.W[2] = nullptr;
  g2.bias[1] = g2.bias[2] = nullptr; g2.C[1] = g2.C[2] = nullptr;
  gemm_nt_bias<1><<<dim3(32, 8, 1), 256, 0, stream>>>(g2);
}

// Round 5
// 150.515 us; speedup vs baseline: 1.5817x; 1.0576x over previous
//
#include <hip/hip_runtime.h>
#include <stdint.h>

typedef unsigned short u16;
typedef __attribute__((ext_vector_type(8))) short bfrag8;       // 8 x bf16 (MFMA operand)
typedef __attribute__((ext_vector_type(4))) float f32x4;        // MFMA accumulator
typedef __attribute__((ext_vector_type(8))) unsigned short u16x8;
typedef __attribute__((ext_vector_type(4))) unsigned short u16x4;

__device__ __forceinline__ u16 f2bf(float f) {
  union { float f; uint32_t u; } v; v.f = f;
  return (u16)((v.u + 0x7FFFu + ((v.u >> 16) & 1u)) >> 16);   // RNE
}

// async global->LDS, 16B per lane; LDS dest is wave-uniform base + lane*16
__device__ __forceinline__ void gload16(const void* g, void* l) {
  __builtin_amdgcn_global_load_lds(
      (const __attribute__((address_space(1))) void*)g,
      (__attribute__((address_space(3))) void*)l, 16, 0, 0);
}

// ---------------- fp32 -> bf16 convert, batched (7 tensors, 1 launch) ----------------
struct CvtJob { const float* src; u16* dst; int n4; };
struct CvtBatch { CvtJob j[7]; };

__global__ void cvt_batch(CvtBatch b) {
  CvtJob jb = b.j[blockIdx.y];
  int i = blockIdx.x * blockDim.x + threadIdx.x;
  if (i >= jb.n4) return;
  float4 v = reinterpret_cast<const float4*>(jb.src)[i];
  u16x4 o;
  o[0] = f2bf(v.x); o[1] = f2bf(v.y); o[2] = f2bf(v.z); o[3] = f2bf(v.w);
  reinterpret_cast<u16x4*>(jb.dst)[i] = o;
}

// ---------------- NT GEMM: C = A(M,K) @ W(N,K)^T + bias, M=4096,N=1024,K=1024 ----------------
struct Gemm3 {
  const u16* A[3];
  const u16* W[3];
  const float* bias[3];
  void* C[3];
};

template<int OUT_F32>
__global__ __launch_bounds__(256, 2) void gemm_nt_bias(Gemm3 g) {
  constexpr int K = 1024, N = 1024;
  constexpr int BK = 32, LDT = BK + 8;   // +8 bf16 pad -> 80B row stride, conflict-free b128 reads
  __shared__ u16 As[128 * LDT];
  __shared__ u16 Bs[128 * LDT];
  const int z = blockIdx.z;
  const u16* __restrict__ A = g.A[z];
  const u16* __restrict__ W = g.W[z];
  const float* __restrict__ bias = g.bias[z];
  const int tid = threadIdx.x;
  const int lane = tid & 63;
  const int lr = lane & 15, lg = lane >> 4;
  const int wave = tid >> 6;
  const int wr = (wave >> 1) * 64, wc = (wave & 1) * 64;  // 2x2 wave grid, 64x64 each
  const int bm = blockIdx.x * 128, bn = blockIdx.y * 128;

  f32x4 acc[4][4] = {};

  for (int k0 = 0; k0 < K; k0 += BK) {
#pragma unroll
    for (int i = 0; i < 2; i++) {
      int u = tid + 256 * i;
      int row = u >> 2, kg = (u & 3) * 8;
      *(u16x8*)&As[row * LDT + kg] = *(const u16x8*)(A + (size_t)(bm + row) * K + k0 + kg);
      *(u16x8*)&Bs[row * LDT + kg] = *(const u16x8*)(W + (size_t)(bn + row) * K + k0 + kg);
    }
    __syncthreads();
    bfrag8 af[4], bf[4];
#pragma unroll
    for (int mi = 0; mi < 4; mi++)
      af[mi] = *(const bfrag8*)&As[(wr + mi * 16 + lr) * LDT + lg * 8];
#pragma unroll
    for (int ni = 0; ni < 4; ni++)
      bf[ni] = *(const bfrag8*)&Bs[(wc + ni * 16 + lr) * LDT + lg * 8];
#pragma unroll
    for (int mi = 0; mi < 4; mi++)
#pragma unroll
      for (int ni = 0; ni < 4; ni++)
        acc[mi][ni] = __builtin_amdgcn_mfma_f32_16x16x32_bf16(af[mi], bf[ni], acc[mi][ni], 0, 0, 0);
    __syncthreads();
  }

  const int col0 = bn + wc + lr;
#pragma unroll
  for (int ni = 0; ni < 4; ni++) {
    int col = col0 + ni * 16;
    float bv = bias[col];
#pragma unroll
    for (int mi = 0; mi < 4; mi++) {
      int row = bm + wr + mi * 16 + lg * 4;
#pragma unroll
      for (int r = 0; r < 4; r++) {
        float v = acc[mi][ni][r] + bv;
        if (OUT_F32)
          ((float*)g.C[z])[(size_t)(row + r) * N + col] = v;
        else
          ((u16*)g.C[z])[(size_t)(row + r) * N + col] = f2bf(v);
      }
    }
  }
}

// ---------------- V transpose: per bh, (2048,64) -> VT[64][2048]; also zeroes work-queue ctrs ----
__global__ void vtrans_kernel(const u16* __restrict__ Vp, u16* __restrict__ VT,
                              unsigned* __restrict__ ctr) {
  if (blockIdx.x == 0 && blockIdx.y == 0 && threadIdx.x < 8) ctr[threadIdx.x * 16] = 0u;
  __shared__ u16 T[64][66];
  const int kt = blockIdx.x, bh = blockIdx.y;
  const int tid = threadIdx.x;
  const u16* src = Vp + (size_t)bh * 131072 + (size_t)kt * 64 * 64;
#pragma unroll
  for (int i = 0; i < 2; i++) {
    int u = tid + 256 * i;
    int row = u >> 3, c = (u & 7) * 8;
    u16x8 v = *(const u16x8*)(src + row * 64 + c);
#pragma unroll
    for (int j = 0; j < 8; j++) T[c + j][row] = v[j];
  }
  __syncthreads();
  u16* dst = VT + (size_t)bh * 131072 + (size_t)kt * 64;
#pragma unroll
  for (int i = 0; i < 2; i++) {
    int u = tid + 256 * i;
    int d = u >> 3, c = (u & 7) * 8;
    u16x8 o = *(const u16x8*)&T[d][c];
    *(u16x8*)(dst + (size_t)d * 2048 + c) = o;
  }
}

// ---------------- causal flash attention, persistent blocks + per-XCD LPT work queues ----------
// Group g = blockIdx.x & 7 (default round-robin wg->XCD mapping) owns heads {4g..4g+3}:
// per-XCD working set 2MB -> L2-hit prefetch. Unit u (0..127): j = 31-(u>>2) heavy-first,
// bh = g*4 + (u&3). Wave w owns q rows [j*64 + w*16, +16); KVBLK=64 double-buffered via
// swizzled global_load_lds (round-3 structure unchanged).
__global__ __launch_bounds__(256, 3) void attn_kernel(
    const u16* __restrict__ Qp, const u16* __restrict__ Kp,
    const u16* __restrict__ VT, u16* __restrict__ X,
    unsigned* __restrict__ ctr)
{
  __shared__ __align__(16) u16 Ks[2][64][64];   // 16 KB
  __shared__ __align__(16) u16 Vs[2][64][64];   // 16 KB  (rows = d, cols = kpos slice)
  constexpr int LDP = 72;                        // 144B stride (9x16B): aligned b128, ~2-way banks
  __shared__ __align__(16) u16 Ps[4][16][LDP];   // 9 KB, per-wave P tile (16 q-rows x 64 kpos)
  __shared__ unsigned s_unit;

  const int tid = threadIdx.x, lane = tid & 63, w = tid >> 6;
  const int lr = lane & 15, lg = lane >> 4;
  const int grp = (int)(blockIdx.x & 7);
  unsigned* __restrict__ gctr = ctr + grp * 16;   // 64B-spaced per-group counters
  // staging geometry: lane -> (row=lane>>3, slot=lane&7); source chunk pre-swizzled so
  // LDS slot s of row r holds global chunk s^(r&7) (linear LDS dest, same XOR on reads)
  const int srow = lane >> 3;
  const int schunk = (lane & 7) ^ srow;
  const float SCALE = 0.03125f;  // 1/sqrt(1024)

  for (;;) {
    __syncthreads();                 // previous unit's LDS reads + s_unit use complete
    if (tid == 0) s_unit = atomicAdd(gctr, 1u);
    __syncthreads();
    const unsigned u = s_unit;
    if (u >= 128u) return;
    const int j = 31 - (int)(u >> 2);           // heavy-first within group
    const int bh = grp * 4 + (int)(u & 3u);     // group-local heads -> XCD L2 locality
    const size_t base = (size_t)bh * 131072;
    const u16* __restrict__ Qb = Qp + base;
    const u16* __restrict__ Kb = Kp + base;
    const u16* __restrict__ Vtb = VT + base;
    const int qrow0 = j * 64 + w * 16;          // wave's first q row

    // Q fragments
    bfrag8 qf[2];
#pragma unroll
    for (int ds = 0; ds < 2; ds++)
      qf[ds] = *(const bfrag8*)(Qb + (size_t)(qrow0 + lr) * 64 + ds * 32 + lg * 8);

    f32x4 oacc[4] = {};
    float m_run[4], l_run[4];
#pragma unroll
    for (int r = 0; r < 4; r++) { m_run[r] = -INFINITY; l_run[r] = 0.f; }

    auto STAGE = [&](int kt, int bufi) {
      const u16* gk = Kb + (size_t)(kt * 64 + w * 16 + srow) * 64 + schunk * 8;
      gload16(gk,       &Ks[bufi][w * 16][0]);
      gload16(gk + 512, &Ks[bufi][w * 16 + 8][0]);
      const u16* gv = Vtb + (size_t)(w * 16 + srow) * 2048 + kt * 64 + schunk * 8;
      gload16(gv,            &Vs[bufi][w * 16][0]);
      gload16(gv + 8 * 2048, &Vs[bufi][w * 16 + 8][0]);
    };

    STAGE(0, 0);
    __syncthreads();   // tile 0 ready
    int buf = 0;

    for (int kt = 0; kt <= j; kt++) {
      if (kt < j) STAGE(kt + 1, buf ^ 1);   // prefetch completes under compute

      // ---- S = Q K^T ----
      f32x4 sacc[4];
#pragma unroll
      for (int kf = 0; kf < 4; kf++) sacc[kf] = (f32x4){0.f, 0.f, 0.f, 0.f};
#pragma unroll
      for (int kf = 0; kf < 4; kf++) {
        const int krow = kf * 16 + lr;
        bfrag8 kb0 = *(const bfrag8*)&Ks[buf][krow][((lg) ^ (krow & 7)) * 8];
        bfrag8 kb1 = *(const bfrag8*)&Ks[buf][krow][((lg + 4) ^ (krow & 7)) * 8];
        sacc[kf] = __builtin_amdgcn_mfma_f32_16x16x32_bf16(qf[0], kb0, sacc[kf], 0, 0, 0);
        sacc[kf] = __builtin_amdgcn_mfma_f32_16x16x32_bf16(qf[1], kb1, sacc[kf], 0, 0, 0);
      }

      // ---- causal mask (only the diagonal tile kt==j can mask) ----
      if (kt == j) {
#pragma unroll
        for (int kf = 0; kf < 4; kf++)
#pragma unroll
          for (int r = 0; r < 4; r++) {
            int qg = qrow0 + lg * 4 + r;
            int kg = kt * 64 + kf * 16 + lr;
            if (kg > qg) sacc[kf][r] = -INFINITY;
          }
      }

      // ---- online softmax (scale folded into exp); P -> per-wave LDS ----
#pragma unroll
      for (int r = 0; r < 4; r++) {
        float mt = fmaxf(fmaxf(sacc[0][r], sacc[1][r]), fmaxf(sacc[2][r], sacc[3][r]));
        mt = fmaxf(mt, __shfl_xor(mt, 1));
        mt = fmaxf(mt, __shfl_xor(mt, 2));
        mt = fmaxf(mt, __shfl_xor(mt, 4));
        mt = fmaxf(mt, __shfl_xor(mt, 8));
        float mnew = fmaxf(m_run[r], mt * SCALE);
        float corr = __expf(m_run[r] - mnew);   // first tile: exp(-inf)=0
        m_run[r] = mnew;
        l_run[r] *= corr;
#pragma unroll
        for (int df = 0; df < 4; df++) oacc[df][r] *= corr;
        float rs = 0.f;
#pragma unroll
        for (int kf = 0; kf < 4; kf++) {
          float p = __expf(__builtin_fmaf(sacc[kf][r], SCALE, -mnew));
          rs += p;
          Ps[w][lg * 4 + r][kf * 16 + lr] = f2bf(p);
        }
        rs += __shfl_xor(rs, 1);
        rs += __shfl_xor(rs, 2);
        rs += __shfl_xor(rs, 4);
        rs += __shfl_xor(rs, 8);
        l_run[r] += rs;
      }

      // ---- O += P V ----
#pragma unroll
      for (int ks = 0; ks < 2; ks++) {
        bfrag8 pa = *(const bfrag8*)&Ps[w][lr][ks * 32 + lg * 8];
#pragma unroll
        for (int df = 0; df < 4; df++) {
          const int vrow = df * 16 + lr;
          bfrag8 vf = *(const bfrag8*)&Vs[buf][vrow][((ks * 4 + lg) ^ (vrow & 7)) * 8];
          oacc[df] = __builtin_amdgcn_mfma_f32_16x16x32_bf16(pa, vf, oacc[df], 0, 0, 0);
        }
      }

      __syncthreads();   // drains prefetch vmcnt + buffer handoff
      buf ^= 1;
    }

    // ---- normalize and write X ----
#pragma unroll
    for (int r = 0; r < 4; r++) {
      float inv = 1.0f / l_run[r];
      int row = qrow0 + lg * 4 + r;
#pragma unroll
      for (int df = 0; df < 4; df++)
        X[base + (size_t)row * 64 + df * 16 + lr] = f2bf(oacc[df][r] * inv);
    }
  }
}

extern "C" void kernel_launch(void* const* d_in, const int* in_sizes, int n_in,
                              void* d_out, int out_size, void* d_ws, size_t ws_size,
                              hipStream_t stream) {
  const float* key   = (const float*)d_in[0];
  const float* query = (const float*)d_in[1];
  const float* value = (const float*)d_in[2];
  const float* Wq = (const float*)d_in[4];
  const float* bq = (const float*)d_in[5];
  const float* Wk = (const float*)d_in[6];
  const float* bk = (const float*)d_in[7];
  const float* Wv = (const float*)d_in[8];
  const float* bv = (const float*)d_in[9];
  const float* Wo = (const float*)d_in[10];
  const float* bo = (const float*)d_in[11];

  u16* ws = (u16*)d_ws;
  const size_t MD = 4096ull * 1024ull;
  u16* qb  = ws;                   // query bf16 (dead after g1; first 512B reused as queue ctrs)
  u16* kb  = ws + MD;
  u16* vbf = ws + 2 * MD;          // value bf16 (reused as VT after g1)
  u16* Qp  = ws + 3 * MD;
  u16* Kp  = ws + 4 * MD;
  u16* Vp  = ws + 5 * MD;
  u16* Xb  = ws + 6 * MD;
  u16* wqb = ws + 7 * MD;
  u16* wkb = wqb + 1024 * 1024;
  u16* wvb = wkb + 1024 * 1024;
  u16* wob = wvb + 1024 * 1024;

  CvtBatch cb;
  cb.j[0] = { query, qb, 1048576 };
  cb.j[1] = { key,   kb, 1048576 };
  cb.j[2] = { value, vbf, 1048576 };
  cb.j[3] = { Wq, wqb, 262144 };
  cb.j[4] = { Wk, wkb, 262144 };
  cb.j[5] = { Wv, wvb, 262144 };
  cb.j[6] = { Wo, wob, 262144 };
  cvt_batch<<<dim3(4096, 7), 256, 0, stream>>>(cb);

  Gemm3 g1;
  g1.A[0] = qb;  g1.A[1] = kb;  g1.A[2] = vbf;
  g1.W[0] = wqb; g1.W[1] = wkb; g1.W[2] = wvb;
  g1.bias[0] = bq; g1.bias[1] = bk; g1.bias[2] = bv;
  g1.C[0] = Qp; g1.C[1] = Kp; g1.C[2] = Vp;
  gemm_nt_bias<0><<<dim3(32, 8, 3), 256, 0, stream>>>(g1);

  u16* VT = vbf;
  unsigned* ctr = (unsigned*)qb;   // qb dead after g1
  vtrans_kernel<<<dim3(32, 32), 256, 0, stream>>>(Vp, VT, ctr);

  attn_kernel<<<768, 256, 0, stream>>>(Qp, Kp, VT, Xb, ctr);

  Gemm3 g2;
  g2.A[0] = Xb; g2.W[0] = wob; g2.bias[0] = bo; g2.C[0] = d_out;
  g2.A[1] = g2.A[2] = nullptr; g2.W[1] = g2.W[2] = nullptr;
  g2.bias[1] = g2.bias[2] = nullptr; g2.C[1] = g2.C[2] = nullptr;
  gemm_nt_bias<1><<<dim3(32, 8, 1), 256, 0, stream>>>(g2);
}

// Round 6
// 130.073 us; speedup vs baseline: 1.8302x; 1.1572x over previous
//
#include <hip/hip_runtime.h>
#include <stdint.h>

typedef unsigned short u16;
typedef __attribute__((ext_vector_type(8))) short bfrag8;       // 8 x bf16 (MFMA operand)
typedef __attribute__((ext_vector_type(4))) float f32x4;        // MFMA accumulator
typedef __attribute__((ext_vector_type(8))) unsigned short u16x8;
typedef __attribute__((ext_vector_type(4))) unsigned short u16x4;

__device__ __forceinline__ u16 f2bf(float f) {
  union { float f; uint32_t u; } v; v.f = f;
  return (u16)((v.u + 0x7FFFu + ((v.u >> 16) & 1u)) >> 16);   // RNE
}

// async global->LDS, 16B per lane; LDS dest is wave-uniform base + lane*16
__device__ __forceinline__ void gload16(const void* g, void* l) {
  __builtin_amdgcn_global_load_lds(
      (const __attribute__((address_space(1))) void*)g,
      (__attribute__((address_space(3))) void*)l, 16, 0, 0);
}

// ---------------- fp32 -> bf16 convert, batched (7 tensors, 1 launch) ----------------
struct CvtJob { const float* src; u16* dst; int n4; };
struct CvtBatch { CvtJob j[7]; };

__global__ void cvt_batch(CvtBatch b) {
  CvtJob jb = b.j[blockIdx.y];
  int i = blockIdx.x * blockDim.x + threadIdx.x;
  if (i >= jb.n4) return;
  float4 v = reinterpret_cast<const float4*>(jb.src)[i];
  u16x4 o;
  o[0] = f2bf(v.x); o[1] = f2bf(v.y); o[2] = f2bf(v.z); o[3] = f2bf(v.w);
  reinterpret_cast<u16x4*>(jb.dst)[i] = o;
}

// ---------------- NT GEMM: C = A(M,K) @ W(N,K)^T + bias, M=4096,N=1024,K=1024 ----------------
struct Gemm3 {
  const u16* A[3];
  const u16* W[3];
  const float* bias[3];
  void* C[3];
};

template<int OUT_F32>
__global__ __launch_bounds__(256, 2) void gemm_nt_bias(Gemm3 g) {
  constexpr int K = 1024, N = 1024;
  constexpr int BK = 32, LDT = BK + 8;   // +8 bf16 pad -> 80B row stride, conflict-free b128 reads
  __shared__ u16 As[128 * LDT];
  __shared__ u16 Bs[128 * LDT];
  const int z = blockIdx.z;
  const u16* __restrict__ A = g.A[z];
  const u16* __restrict__ W = g.W[z];
  const float* __restrict__ bias = g.bias[z];
  const int tid = threadIdx.x;
  const int lane = tid & 63;
  const int lr = lane & 15, lg = lane >> 4;
  const int wave = tid >> 6;
  const int wr = (wave >> 1) * 64, wc = (wave & 1) * 64;  // 2x2 wave grid, 64x64 each
  const int bm = blockIdx.x * 128, bn = blockIdx.y * 128;

  f32x4 acc[4][4] = {};

  for (int k0 = 0; k0 < K; k0 += BK) {
#pragma unroll
    for (int i = 0; i < 2; i++) {
      int u = tid + 256 * i;
      int row = u >> 2, kg = (u & 3) * 8;
      *(u16x8*)&As[row * LDT + kg] = *(const u16x8*)(A + (size_t)(bm + row) * K + k0 + kg);
      *(u16x8*)&Bs[row * LDT + kg] = *(const u16x8*)(W + (size_t)(bn + row) * K + k0 + kg);
    }
    __syncthreads();
    bfrag8 af[4], bf[4];
#pragma unroll
    for (int mi = 0; mi < 4; mi++)
      af[mi] = *(const bfrag8*)&As[(wr + mi * 16 + lr) * LDT + lg * 8];
#pragma unroll
    for (int ni = 0; ni < 4; ni++)
      bf[ni] = *(const bfrag8*)&Bs[(wc + ni * 16 + lr) * LDT + lg * 8];
#pragma unroll
    for (int mi = 0; mi < 4; mi++)
#pragma unroll
      for (int ni = 0; ni < 4; ni++)
        acc[mi][ni] = __builtin_amdgcn_mfma_f32_16x16x32_bf16(af[mi], bf[ni], acc[mi][ni], 0, 0, 0);
    __syncthreads();
  }

  const int col0 = bn + wc + lr;
#pragma unroll
  for (int ni = 0; ni < 4; ni++) {
    int col = col0 + ni * 16;
    float bv = bias[col];
#pragma unroll
    for (int mi = 0; mi < 4; mi++) {
      int row = bm + wr + mi * 16 + lg * 4;
#pragma unroll
      for (int r = 0; r < 4; r++) {
        float v = acc[mi][ni][r] + bv;
        if (OUT_F32)
          ((float*)g.C[z])[(size_t)(row + r) * N + col] = v;
        else
          ((u16*)g.C[z])[(size_t)(row + r) * N + col] = f2bf(v);
      }
    }
  }
}

// ---------------- V transpose: per bh, (2048,64) -> VT[64][2048]; also zeroes work-queue ctrs ----
__global__ void vtrans_kernel(const u16* __restrict__ Vp, u16* __restrict__ VT,
                              unsigned* __restrict__ ctr) {
  if (blockIdx.x == 0 && blockIdx.y == 0 && threadIdx.x < 8) ctr[threadIdx.x * 16] = 0u;
  __shared__ u16 T[64][66];
  const int kt = blockIdx.x, bh = blockIdx.y;
  const int tid = threadIdx.x;
  const u16* src = Vp + (size_t)bh * 131072 + (size_t)kt * 64 * 64;
#pragma unroll
  for (int i = 0; i < 2; i++) {
    int u = tid + 256 * i;
    int row = u >> 3, c = (u & 7) * 8;
    u16x8 v = *(const u16x8*)(src + row * 64 + c);
#pragma unroll
    for (int j = 0; j < 8; j++) T[c + j][row] = v[j];
  }
  __syncthreads();
  u16* dst = VT + (size_t)bh * 131072 + (size_t)kt * 64;
#pragma unroll
  for (int i = 0; i < 2; i++) {
    int u = tid + 256 * i;
    int d = u >> 3, c = (u & 7) * 8;
    u16x8 o = *(const u16x8*)&T[d][c];
    *(u16x8*)(dst + (size_t)d * 2048 + c) = o;
  }
}

// ---------------- causal flash attention, persistent blocks + per-XCD LPT work queues ----------
// Swapped-operand form (T12): S^T = mfma(K,Q) puts each q-row's scores lane-local
// (q = lr, kpos = kf*16+lg*4+r) -> softmax reduce = in-lane tree + 2 shfls.
// O^T = mfma(V,P) puts oacc col = q -> corr/l are per-lane scalars.
// All LDS/global access patterns identical to round-5 (A/B frags share per-lane layout).
__global__ __launch_bounds__(256, 3) void attn_kernel(
    const u16* __restrict__ Qp, const u16* __restrict__ Kp,
    const u16* __restrict__ VT, u16* __restrict__ X,
    unsigned* __restrict__ ctr)
{
  __shared__ __align__(16) u16 Ks[2][64][64];   // 16 KB
  __shared__ __align__(16) u16 Vs[2][64][64];   // 16 KB  (rows = d, cols = kpos slice)
  constexpr int LDP = 72;                        // 144B stride (9x16B): aligned b128, ~2-way banks
  __shared__ __align__(16) u16 Ps[4][16][LDP];   // 9 KB, per-wave P tile (16 q-rows x 64 kpos)
  __shared__ unsigned s_unit;

  const int tid = threadIdx.x, lane = tid & 63, w = tid >> 6;
  const int lr = lane & 15, lg = lane >> 4;
  const int grp = (int)(blockIdx.x & 7);
  unsigned* __restrict__ gctr = ctr + grp * 16;   // 64B-spaced per-group counters
  // staging geometry: lane -> (row=lane>>3, slot=lane&7); source chunk pre-swizzled so
  // LDS slot s of row r holds global chunk s^(r&7) (linear LDS dest, same XOR on reads)
  const int srow = lane >> 3;
  const int schunk = (lane & 7) ^ srow;
  const float SCALE = 0.03125f;  // 1/sqrt(1024)

  for (;;) {
    __syncthreads();                 // previous unit's LDS reads + s_unit use complete
    if (tid == 0) s_unit = atomicAdd(gctr, 1u);
    __syncthreads();
    const unsigned u = s_unit;
    if (u >= 128u) return;
    const int j = 31 - (int)(u >> 2);           // heavy-first within group
    const int bh = grp * 4 + (int)(u & 3u);     // group-local heads -> XCD L2 locality
    const size_t base = (size_t)bh * 131072;
    const u16* __restrict__ Qb = Qp + base;
    const u16* __restrict__ Kb = Kp + base;
    const u16* __restrict__ Vtb = VT + base;
    const int qrow0 = j * 64 + w * 16;          // wave's first q row
    const int q = qrow0 + lr;                   // this lane's q row (swapped layout)

    // Q fragments (B-operand: lane holds Q[qrow0+lr][lg*8..+8] per 32-chunk)
    bfrag8 qf[2];
#pragma unroll
    for (int ds = 0; ds < 2; ds++)
      qf[ds] = *(const bfrag8*)(Qb + (size_t)(qrow0 + lr) * 64 + ds * 32 + lg * 8);

    f32x4 oacc[4] = {};                          // O^T: col=q(lr), row d=df*16+lg*4+r
    float m_run = -INFINITY, l_run = 0.f;        // per-lane scalars (own q-row)

    auto STAGE = [&](int kt, int bufi) {
      const u16* gk = Kb + (size_t)(kt * 64 + w * 16 + srow) * 64 + schunk * 8;
      gload16(gk,       &Ks[bufi][w * 16][0]);
      gload16(gk + 512, &Ks[bufi][w * 16 + 8][0]);
      const u16* gv = Vtb + (size_t)(w * 16 + srow) * 2048 + kt * 64 + schunk * 8;
      gload16(gv,            &Vs[bufi][w * 16][0]);
      gload16(gv + 8 * 2048, &Vs[bufi][w * 16 + 8][0]);
    };

    STAGE(0, 0);
    __syncthreads();   // tile 0 ready
    int buf = 0;

    for (int kt = 0; kt <= j; kt++) {
      if (kt < j) STAGE(kt + 1, buf ^ 1);   // prefetch completes under compute

      // ---- S^T = K Q^T : sacc[kf][r] = S[kpos = kt*64+kf*16+lg*4+r][q] ----
      f32x4 sacc[4];
#pragma unroll
      for (int kf = 0; kf < 4; kf++) sacc[kf] = (f32x4){0.f, 0.f, 0.f, 0.f};
#pragma unroll
      for (int kf = 0; kf < 4; kf++) {
        const int krow = kf * 16 + lr;
        bfrag8 kb0 = *(const bfrag8*)&Ks[buf][krow][((lg) ^ (krow & 7)) * 8];
        bfrag8 kb1 = *(const bfrag8*)&Ks[buf][krow][((lg + 4) ^ (krow & 7)) * 8];
        sacc[kf] = __builtin_amdgcn_mfma_f32_16x16x32_bf16(kb0, qf[0], sacc[kf], 0, 0, 0);
        sacc[kf] = __builtin_amdgcn_mfma_f32_16x16x32_bf16(kb1, qf[1], sacc[kf], 0, 0, 0);
      }

      // ---- causal mask (only the diagonal tile kt==j can mask) ----
      if (kt == j) {
#pragma unroll
        for (int kf = 0; kf < 4; kf++)
#pragma unroll
          for (int r = 0; r < 4; r++) {
            int kg = kt * 64 + kf * 16 + lg * 4 + r;
            if (kg > q) sacc[kf][r] = -INFINITY;
          }
      }

      // ---- online softmax: in-lane tree + 2 shfls (reduce over lg: lanes lr,lr+16,+32,+48) ----
      float mx01, mx23, smax;
      {
        f32x4 m2 = (f32x4){fmaxf(sacc[0][0], sacc[0][1]), fmaxf(sacc[0][2], sacc[0][3]),
                           fmaxf(sacc[1][0], sacc[1][1]), fmaxf(sacc[1][2], sacc[1][3])};
        f32x4 m3 = (f32x4){fmaxf(sacc[2][0], sacc[2][1]), fmaxf(sacc[2][2], sacc[2][3]),
                           fmaxf(sacc[3][0], sacc[3][1]), fmaxf(sacc[3][2], sacc[3][3])};
        mx01 = fmaxf(fmaxf(m2[0], m2[1]), fmaxf(m2[2], m2[3]));
        mx23 = fmaxf(fmaxf(m3[0], m3[1]), fmaxf(m3[2], m3[3]));
        smax = fmaxf(mx01, mx23);
      }
      smax = fmaxf(smax, __shfl_xor(smax, 16));
      smax = fmaxf(smax, __shfl_xor(smax, 32));

      float mnew = fmaxf(m_run, smax * SCALE);
      float corr = __expf(m_run - mnew);   // first tile: exp(-inf)=0
      m_run = mnew;
#pragma unroll
      for (int df = 0; df < 4; df++)
#pragma unroll
        for (int r = 0; r < 4; r++) oacc[df][r] *= corr;

      float rs = 0.f;
#pragma unroll
      for (int kf = 0; kf < 4; kf++) {
        float p0 = __expf(__builtin_fmaf(sacc[kf][0], SCALE, -mnew));
        float p1 = __expf(__builtin_fmaf(sacc[kf][1], SCALE, -mnew));
        float p2 = __expf(__builtin_fmaf(sacc[kf][2], SCALE, -mnew));
        float p3 = __expf(__builtin_fmaf(sacc[kf][3], SCALE, -mnew));
        rs += (p0 + p1) + (p2 + p3);
        Ps[w][lr][kf * 16 + lg * 4 + 0] = f2bf(p0);
        Ps[w][lr][kf * 16 + lg * 4 + 1] = f2bf(p1);
        Ps[w][lr][kf * 16 + lg * 4 + 2] = f2bf(p2);
        Ps[w][lr][kf * 16 + lg * 4 + 3] = f2bf(p3);
      }
      rs += __shfl_xor(rs, 16);
      rs += __shfl_xor(rs, 32);
      l_run = l_run * corr + rs;

      // ---- O^T += V^T P : A = VT rows (d), B = Ps rows (q) ----
#pragma unroll
      for (int ks = 0; ks < 2; ks++) {
        bfrag8 pa = *(const bfrag8*)&Ps[w][lr][ks * 32 + lg * 8];
#pragma unroll
        for (int df = 0; df < 4; df++) {
          const int vrow = df * 16 + lr;
          bfrag8 vf = *(const bfrag8*)&Vs[buf][vrow][((ks * 4 + lg) ^ (vrow & 7)) * 8];
          oacc[df] = __builtin_amdgcn_mfma_f32_16x16x32_bf16(vf, pa, oacc[df], 0, 0, 0);
        }
      }

      __syncthreads();   // drains prefetch vmcnt + buffer handoff
      buf ^= 1;
    }

    // ---- normalize and write X (O^T: lane owns q=qrow0+lr, d=df*16+lg*4+r) ----
    float inv = 1.0f / l_run;
#pragma unroll
    for (int df = 0; df < 4; df++)
#pragma unroll
      for (int r = 0; r < 4; r++)
        X[base + (size_t)q * 64 + df * 16 + lg * 4 + r] = f2bf(oacc[df][r] * inv);
  }
}

extern "C" void kernel_launch(void* const* d_in, const int* in_sizes, int n_in,
                              void* d_out, int out_size, void* d_ws, size_t ws_size,
                              hipStream_t stream) {
  const float* key   = (const float*)d_in[0];
  const float* query = (const float*)d_in[1];
  const float* value = (const float*)d_in[2];
  const float* Wq = (const float*)d_in[4];
  const float* bq = (const float*)d_in[5];
  const float* Wk = (const float*)d_in[6];
  const float* bk = (const float*)d_in[7];
  const float* Wv = (const float*)d_in[8];
  const float* bv = (const float*)d_in[9];
  const float* Wo = (const float*)d_in[10];
  const float* bo = (const float*)d_in[11];

  u16* ws = (u16*)d_ws;
  const size_t MD = 4096ull * 1024ull;
  u16* qb  = ws;                   // query bf16 (dead after g1; first 512B reused as queue ctrs)
  u16* kb  = ws + MD;
  u16* vbf = ws + 2 * MD;          // value bf16 (reused as VT after g1)
  u16* Qp  = ws + 3 * MD;
  u16* Kp  = ws + 4 * MD;
  u16* Vp  = ws + 5 * MD;
  u16* Xb  = ws + 6 * MD;
  u16* wqb = ws + 7 * MD;
  u16* wkb = wqb + 1024 * 1024;
  u16* wvb = wkb + 1024 * 1024;
  u16* wob = wvb + 1024 * 1024;

  CvtBatch cb;
  cb.j[0] = { query, qb, 1048576 };
  cb.j[1] = { key,   kb, 1048576 };
  cb.j[2] = { value, vbf, 1048576 };
  cb.j[3] = { Wq, wqb, 262144 };
  cb.j[4] = { Wk, wkb, 262144 };
  cb.j[5] = { Wv, wvb, 262144 };
  cb.j[6] = { Wo, wob, 262144 };
  cvt_batch<<<dim3(4096, 7), 256, 0, stream>>>(cb);

  Gemm3 g1;
  g1.A[0] = qb;  g1.A[1] = kb;  g1.A[2] = vbf;
  g1.W[0] = wqb; g1.W[1] = wkb; g1.W[2] = wvb;
  g1.bias[0] = bq; g1.bias[1] = bk; g1.bias[2] = bv;
  g1.C[0] = Qp; g1.C[1] = Kp; g1.C[2] = Vp;
  gemm_nt_bias<0><<<dim3(32, 8, 3), 256, 0, stream>>>(g1);

  u16* VT = vbf;
  unsigned* ctr = (unsigned*)qb;   // qb dead after g1
  vtrans_kernel<<<dim3(32, 32), 256, 0, stream>>>(Vp, VT, ctr);

  attn_kernel<<<768, 256, 0, stream>>>(Qp, Kp, VT, Xb, ctr);

  Gemm3 g2;
  g2.A[0] = Xb; g2.W[0] = wob; g2.bias[0] = bo; g2.C[0] = d_out;
  g2.A[1] = g2.A[2] = nullptr; g2.W[1] = g2.W[2] = nullptr;
  g2.bias[1] = g2.bias[2] = nullptr; g2.C[1] = g2.C[2] = nullptr;
  gemm_nt_bias<1><<<dim3(32, 8, 1), 256, 0, stream>>>(g2);
}